// Round 4
// baseline (739.131 us; speedup 1.0000x reference)
//
#include <hip/hip_runtime.h>
#include <hip/hip_bf16.h>
#include <stdint.h>

#define T_STEPS 86
#define HDIM    64
#define VOCABSZ 257
#define ROWS    8         // batch rows per block -> 512 blocks = 2 per CU
#define NTHREADS 512      // 8 waves

typedef __attribute__((ext_vector_type(8))) short short8;
typedef __attribute__((ext_vector_type(4))) float f32x4;

__device__ __forceinline__ ushort f2bf(float x){
    union { float f; uint32_t u; } v; v.f = x;
    uint32_t r = v.u + 0x7fffu + ((v.u >> 16) & 1u);
    return (ushort)(r >> 16);
}
__device__ __forceinline__ float bf2f(ushort h){
    union { uint32_t u; float f; } v; v.u = ((uint32_t)h) << 16;
    return v.f;
}
__device__ __forceinline__ float sig_(float x){
    return __fdividef(1.f, 1.f + __expf(-x));
}
__device__ __forceinline__ float tanh_(float x){
    float e = __expf(2.f * x);
    return 1.f - __fdividef(2.f, e + 1.f);
}

// Register budget: gate W hi+lo (64 VGPR) + lm_W hi only, 2 tiles/wave (16 VGPR)
// + biases/temps ~ <=110 total incl AGPR. (512,4) caps at 128/wave -> 2 blocks/CU.
// R2 lesson: only safe because natural pressure is now well under the cap.
__global__ __launch_bounds__(NTHREADS, 4) void lstm_fused(
    const int*   __restrict__ idx,
    const float* __restrict__ wte,
    const float* __restrict__ W_ih,
    const float* __restrict__ W_hh,
    const float* __restrict__ b_ih,
    const float* __restrict__ b_hh,
    const float* __restrict__ lm_W,
    const float* __restrict__ lm_b,
    float*       __restrict__ out,
    int B)
{
    // A operand staging: [16][128] bf16 (rows 8..15 permanently zero).
    // [0:64)=emb(t), [64:128)=h(t-1). XOR-swizzled.
    __shared__ __align__(16) ushort a_hi[16 * 128];
    __shared__ __align__(16) ushort a_lo[16 * 128];
    __shared__ float g_lds[ROWS * 260];     // gate preactivations bounce (8 rows)
    __shared__ int   idx_lds[ROWS][T_STEPS];

    const int tid  = threadIdx.x;
    const int wave = tid >> 6;
    const int lane = tid & 63;
    const int lmod = lane & 15;
    const int lhi  = lane >> 4;
    const int rbase = blockIdx.x * ROWS;

    // ---- pack gate-weight B-frags into registers (wave owns gate cols [wave*32, wave*32+32)) ----
    // B-frag layout: lane holds B[k = (lane>>4)*8 + e][col = lane&15]
    short8 wbh[2][4], wbl[2][4];
    float  gbias[2];
#pragma unroll
    for (int n = 0; n < 2; ++n) {
        const int col = wave * 32 + n * 16 + lmod;
        gbias[n] = b_ih[col] + b_hh[col];
#pragma unroll
        for (int kt = 0; kt < 4; ++kt) {
            const int k0 = (kt & 1) * 32 + lhi * 8;
            const float* src = (kt < 2 ? W_ih : W_hh) + col * HDIM + k0;
            short8 h8, l8;
#pragma unroll
            for (int e = 0; e < 8; ++e) {
                float f   = src[e];
                ushort hh = f2bf(f);
                h8[e] = (short)hh;
                l8[e] = (short)f2bf(f - bf2f(hh));
            }
            wbh[n][kt] = h8; wbl[n][kt] = l8;
        }
    }

    // ---- pack lm_W B-frags, HI ONLY, exactly 2 tiles/wave (cols 32w..32w+31).
    // Column 256 handled separately in exact fp32 via wave reduction.
    short8 lmh[2][2];
    float  lmbias[2];
#pragma unroll
    for (int ni = 0; ni < 2; ++ni) {
        const int v = (2 * wave + ni) * 16 + lmod;   // < 256 always
        lmbias[ni] = lm_b[v];
#pragma unroll
        for (int kt = 0; kt < 2; ++kt) {
            const int k0 = kt * 32 + lhi * 8;
            short8 h8;
#pragma unroll
            for (int e = 0; e < 8; ++e) h8[e] = (short)f2bf(lm_W[v * HDIM + k0 + e]);
            lmh[ni][kt] = h8;
        }
    }
    const float w256r = lm_W[256 * HDIM + lane];   // per-lane element of last vocab row
    const float b256  = lm_b[256];

    // ---- stage idx slice; zero A-tile ----
    for (int i = tid; i < 16 * 128; i += NTHREADS) { a_hi[i] = 0; a_lo[i] = 0; }
    for (int i = tid; i < ROWS * T_STEPS; i += NTHREADS) {
        const int r = i / T_STEPS, tt = i % T_STEPS;
        idx_lds[r][tt] = idx[(rbase + r) * T_STEPS + tt];
    }
    __syncthreads();

    // ---- stage emb(t=0) ----
    if (tid < ROWS * 16) {
        const int r = tid >> 4, j4 = (tid & 15) * 4;
        const int token = idx_lds[r][0];
        const float4 vv = *(const float4*)(wte + (size_t)token * HDIM + j4);
        const float fv[4] = {vv.x, vv.y, vv.z, vv.w};
#pragma unroll
        for (int e = 0; e < 4; ++e) {
            const ushort hh = f2bf(fv[e]);
            const int ix = (r * 128 + j4 + e) ^ ((r & 7) << 3);
            a_hi[ix] = hh;
            a_lo[ix] = f2bf(fv[e] - bf2f(hh));
        }
    }
    __syncthreads();

    float cstate = 0.f;

    for (int t = 0; t < T_STEPS; ++t) {
        // ---- gates MFMA: [8(pad16) x 128] @ [128 x 256] (3-term bf16 split) ----
        f32x4 acc0 = {gbias[0], gbias[0], gbias[0], gbias[0]};
        f32x4 acc1 = {gbias[1], gbias[1], gbias[1], gbias[1]};
#pragma unroll
        for (int kt = 0; kt < 4; ++kt) {
            const int ix = (lmod * 128 + kt * 32 + lhi * 8) ^ ((lmod & 7) << 3);
            const short8 ah = *(const short8*)(a_hi + ix);
            const short8 al = *(const short8*)(a_lo + ix);
            acc0 = __builtin_amdgcn_mfma_f32_16x16x32_bf16(ah, wbh[0][kt], acc0, 0, 0, 0);
            acc0 = __builtin_amdgcn_mfma_f32_16x16x32_bf16(ah, wbl[0][kt], acc0, 0, 0, 0);
            acc0 = __builtin_amdgcn_mfma_f32_16x16x32_bf16(al, wbh[0][kt], acc0, 0, 0, 0);
            acc1 = __builtin_amdgcn_mfma_f32_16x16x32_bf16(ah, wbh[1][kt], acc1, 0, 0, 0);
            acc1 = __builtin_amdgcn_mfma_f32_16x16x32_bf16(ah, wbl[1][kt], acc1, 0, 0, 0);
            acc1 = __builtin_amdgcn_mfma_f32_16x16x32_bf16(al, wbh[1][kt], acc1, 0, 0, 0);
        }
        // D layout: row = (lane>>4)*4 + e, col = lane&15; only rows 0..7 are real
        if (lhi < 2) {
#pragma unroll
            for (int e = 0; e < 4; ++e) {
                const int row = lhi * 4 + e;
                g_lds[row * 260 + wave * 32 + lmod]      = acc0[e];
                g_lds[row * 260 + wave * 32 + 16 + lmod] = acc1[e];
            }
        }
        __syncthreads();   // B2: g_lds ready; a_lds free for overwrite

        // ---- issue emb(t+1) gather early (hide L2 latency under LSTM math) ----
        float4 vv;
        const bool do_stage = (t + 1 < T_STEPS) && (tid < ROWS * 16);
        const int sr = tid >> 4, sj4 = (tid & 15) * 4;
        if (do_stage) {
            const int token = idx_lds[sr][t + 1];
            vv = *(const float4*)(wte + (size_t)token * HDIM + sj4);
        }

        // ---- elementwise LSTM (c in regs), row = wave, col = lane ----
        {
            const float* gr = g_lds + wave * 260;
            const float iv = gr[lane];
            const float fv = gr[64 + lane];
            const float gv = gr[128 + lane];
            const float ov = gr[192 + lane];
            const float cn = sig_(fv) * cstate + sig_(iv) * tanh_(gv);
            cstate = cn;
            const float hv = sig_(ov) * tanh_(cn);
            const ushort hh = f2bf(hv);
            const int ix = (wave * 128 + 64 + lane) ^ ((wave & 7) << 3);
            a_hi[ix] = hh;
            a_lo[ix] = f2bf(hv - bf2f(hh));

            // ---- vocab column 256, exact fp32: dot(h[wave], lm_W[256]) ----
            float p256 = hv * w256r;
#pragma unroll
            for (int off = 32; off; off >>= 1) p256 += __shfl_xor(p256, off);
            if (lane == 0)
                out[(size_t)(rbase + wave) * (T_STEPS * VOCABSZ) + (size_t)t * VOCABSZ + 256]
                    = p256 + b256;
        }
        // ---- write emb(t+1) ----
        if (do_stage) {
            const float fv[4] = {vv.x, vv.y, vv.z, vv.w};
#pragma unroll
            for (int e = 0; e < 4; ++e) {
                const ushort hh = f2bf(fv[e]);
                const int ix = (sr * 128 + sj4 + e) ^ ((sr & 7) << 3);
                a_hi[ix] = hh;
                a_lo[ix] = f2bf(fv[e] - bf2f(hh));
            }
        }
        __syncthreads();   // B3: h(t) + emb(t+1) visible

        // ---- logits MFMA: [8(pad16) x 64] @ [64 x 256], 2-term (exact in h) ----
        short8 lah[2], lal[2];
#pragma unroll
        for (int kt = 0; kt < 2; ++kt) {
            const int ix = (lmod * 128 + 64 + kt * 32 + lhi * 8) ^ ((lmod & 7) << 3);
            lah[kt] = *(const short8*)(a_hi + ix);
            lal[kt] = *(const short8*)(a_lo + ix);
        }
#pragma unroll
        for (int ni = 0; ni < 2; ++ni) {
            f32x4 acc = {lmbias[ni], lmbias[ni], lmbias[ni], lmbias[ni]};
#pragma unroll
            for (int kt = 0; kt < 2; ++kt) {
                acc = __builtin_amdgcn_mfma_f32_16x16x32_bf16(lah[kt], lmh[ni][kt], acc, 0, 0, 0);
                acc = __builtin_amdgcn_mfma_f32_16x16x32_bf16(lal[kt], lmh[ni][kt], acc, 0, 0, 0);
            }
            const int v = (2 * wave + ni) * 16 + lmod;
            if (lhi < 2) {
#pragma unroll
                for (int e = 0; e < 4; ++e) {
                    const int r = rbase + lhi * 4 + e;
                    out[(size_t)r * (T_STEPS * VOCABSZ) + (size_t)t * VOCABSZ + v] = acc[e];
                }
            }
        }
        // no barrier here: a_lds is only read until B2 of the next iteration.
    }
}

extern "C" void kernel_launch(void* const* d_in, const int* in_sizes, int n_in,
                              void* d_out, int out_size, void* d_ws, size_t ws_size,
                              hipStream_t stream) {
    const int*   idx  = (const int*)  d_in[0];
    const float* wte  = (const float*)d_in[1];
    const float* W_ih = (const float*)d_in[2];
    const float* W_hh = (const float*)d_in[3];
    const float* b_ih = (const float*)d_in[4];
    const float* b_hh = (const float*)d_in[5];
    const float* lm_W = (const float*)d_in[6];
    const float* lm_b = (const float*)d_in[7];
    float* out = (float*)d_out;

    const int B = in_sizes[0] / T_STEPS;   // 4096
    const int grid = B / ROWS;             // 512 blocks -> 2 per CU

    lstm_fused<<<grid, NTHREADS, 0, stream>>>(idx, wte, W_ih, W_hh, b_ih, b_hh,
                                              lm_W, lm_b, out, B);
}

// Round 5
// 270.469 us; speedup vs baseline: 2.7328x; 2.7328x over previous
//
#include <hip/hip_runtime.h>
#include <hip/hip_bf16.h>
#include <stdint.h>

#define T_STEPS 86
#define HDIM    64
#define VOCABSZ 257

typedef __attribute__((ext_vector_type(8))) short short8;
typedef __attribute__((ext_vector_type(4))) float f32x4;

__device__ __forceinline__ ushort f2bf(float x){
    union { float f; uint32_t u; } v; v.f = x;
    uint32_t r = v.u + 0x7fffu + ((v.u >> 16) & 1u);
    return (ushort)(r >> 16);
}
__device__ __forceinline__ float bf2f(ushort h){
    union { uint32_t u; float f; } v; v.u = ((uint32_t)h) << 16;
    return v.f;
}
__device__ __forceinline__ float sig_(float x){
    return __fdividef(1.f, 1.f + __expf(-x));
}
__device__ __forceinline__ float tanh_(float x){
    float e = __expf(2.f * x);
    return 1.f - __fdividef(2.f, e + 1.f);
}

// ================= Kernel A: recurrence only (16 rows/block, 8 waves) ========
// Per step: gates MFMA (3-term bf16 split) -> B2 -> elementwise (c in regs) +
// packed h store (hi|lo bf16 in one dword) + emb(t+1) prefetch -> B3.
// No logits work in the serial loop -> short chain, tiny store drain.
__global__ __launch_bounds__(512) void lstm_recur(
    const int*   __restrict__ idx,
    const float* __restrict__ wte,
    const float* __restrict__ W_ih,
    const float* __restrict__ W_hh,
    const float* __restrict__ b_ih,
    const float* __restrict__ b_hh,
    uint32_t*    __restrict__ h_pack)   // [B][T][H] dwords: hi | lo<<16
{
    __shared__ __align__(16) ushort a_hi[16 * 128];
    __shared__ __align__(16) ushort a_lo[16 * 128];
    __shared__ float g_lds[16 * 260];
    __shared__ int   idx_lds[16][T_STEPS];

    const int tid  = threadIdx.x;
    const int wave = tid >> 6;
    const int lane = tid & 63;
    const int lmod = lane & 15;
    const int lhi  = lane >> 4;
    const int rbase = blockIdx.x * 16;

    // pack gate-weight B-frags (wave owns gate cols [wave*32, wave*32+32))
    short8 wbh[2][4], wbl[2][4];
    float  gbias[2];
#pragma unroll
    for (int n = 0; n < 2; ++n) {
        const int col = wave * 32 + n * 16 + lmod;
        gbias[n] = b_ih[col] + b_hh[col];
#pragma unroll
        for (int kt = 0; kt < 4; ++kt) {
            const int k0 = (kt & 1) * 32 + lhi * 8;
            const float* src = (kt < 2 ? W_ih : W_hh) + col * HDIM + k0;
            short8 h8, l8;
#pragma unroll
            for (int e = 0; e < 8; ++e) {
                float f   = src[e];
                ushort hh = f2bf(f);
                h8[e] = (short)hh;
                l8[e] = (short)f2bf(f - bf2f(hh));
            }
            wbh[n][kt] = h8; wbl[n][kt] = l8;
        }
    }

    // stage idx slice; zero A-tile
    for (int i = tid; i < 16 * 128; i += 512) { a_hi[i] = 0; a_lo[i] = 0; }
    for (int i = tid; i < 16 * T_STEPS; i += 512) {
        const int r = i / T_STEPS, tt = i % T_STEPS;
        idx_lds[r][tt] = idx[(rbase + r) * T_STEPS + tt];
    }
    __syncthreads();

    // stage emb(t=0)
    if (tid < 16 * 16) {
        const int r = tid >> 4, j4 = (tid & 15) * 4;
        const int token = idx_lds[r][0];
        const float4 vv = *(const float4*)(wte + (size_t)token * HDIM + j4);
        const float fv[4] = {vv.x, vv.y, vv.z, vv.w};
#pragma unroll
        for (int e = 0; e < 4; ++e) {
            const ushort hh = f2bf(fv[e]);
            const int ix = (r * 128 + j4 + e) ^ ((r & 7) << 3);
            a_hi[ix] = hh;
            a_lo[ix] = f2bf(fv[e] - bf2f(hh));
        }
    }
    __syncthreads();

    float cstate[2] = {0.f, 0.f};

    for (int t = 0; t < T_STEPS; ++t) {
        // gates MFMA: [16 x 128] @ [128 x 256], 3-term bf16 split
        f32x4 acc0 = {gbias[0], gbias[0], gbias[0], gbias[0]};
        f32x4 acc1 = {gbias[1], gbias[1], gbias[1], gbias[1]};
#pragma unroll
        for (int kt = 0; kt < 4; ++kt) {
            const int ix = (lmod * 128 + kt * 32 + lhi * 8) ^ ((lmod & 7) << 3);
            const short8 ah = *(const short8*)(a_hi + ix);
            const short8 al = *(const short8*)(a_lo + ix);
            acc0 = __builtin_amdgcn_mfma_f32_16x16x32_bf16(ah, wbh[0][kt], acc0, 0, 0, 0);
            acc0 = __builtin_amdgcn_mfma_f32_16x16x32_bf16(ah, wbl[0][kt], acc0, 0, 0, 0);
            acc0 = __builtin_amdgcn_mfma_f32_16x16x32_bf16(al, wbh[0][kt], acc0, 0, 0, 0);
            acc1 = __builtin_amdgcn_mfma_f32_16x16x32_bf16(ah, wbh[1][kt], acc1, 0, 0, 0);
            acc1 = __builtin_amdgcn_mfma_f32_16x16x32_bf16(ah, wbl[1][kt], acc1, 0, 0, 0);
            acc1 = __builtin_amdgcn_mfma_f32_16x16x32_bf16(al, wbh[1][kt], acc1, 0, 0, 0);
        }
        // D: row = lhi*4+e, col = lmod (all 16 rows valid)
#pragma unroll
        for (int e = 0; e < 4; ++e) {
            const int row = lhi * 4 + e;
            g_lds[row * 260 + wave * 32 + lmod]      = acc0[e];
            g_lds[row * 260 + wave * 32 + 16 + lmod] = acc1[e];
        }
        __syncthreads();   // B2: g ready; a_lds free for overwrite

        // issue emb(t+1) gather early
        float4 vv;
        const bool do_stage = (t + 1 < T_STEPS) && (tid < 16 * 16);
        const int sr = tid >> 4, sj4 = (tid & 15) * 4;
        if (do_stage) {
            const int token = idx_lds[sr][t + 1];
            vv = *(const float4*)(wte + (size_t)token * HDIM + sj4);
        }

        // elementwise LSTM: rows = wave and wave+8
#pragma unroll
        for (int p = 0; p < 2; ++p) {
            const int r = wave + p * 8;
            const float* gr = g_lds + r * 260;
            const float iv = gr[lane];
            const float fv = gr[64 + lane];
            const float gv = gr[128 + lane];
            const float ov = gr[192 + lane];
            const float cn = sig_(fv) * cstate[p] + sig_(iv) * tanh_(gv);
            cstate[p] = cn;
            const float hv = sig_(ov) * tanh_(cn);
            const ushort hh = f2bf(hv);
            const ushort hl = f2bf(hv - bf2f(hh));
            const int ix = (r * 128 + 64 + lane) ^ ((r & 7) << 3);
            a_hi[ix] = hh;
            a_lo[ix] = hl;
            h_pack[((size_t)(rbase + r) * T_STEPS + t) * HDIM + lane]
                = (uint32_t)hh | ((uint32_t)hl << 16);
        }
        // write emb(t+1)
        if (do_stage) {
            const float fv[4] = {vv.x, vv.y, vv.z, vv.w};
#pragma unroll
            for (int e = 0; e < 4; ++e) {
                const ushort hh = f2bf(fv[e]);
                const int ix = (sr * 128 + sj4 + e) ^ ((sr & 7) << 3);
                a_hi[ix] = hh;
                a_lo[ix] = f2bf(fv[e] - bf2f(hh));
            }
        }
        __syncthreads();   // B3: h(t) + emb(t+1) visible (drains tiny h stores)
    }
}

// ================= Kernel B: logits GEMM [B*T x 64] @ [64 x 257] =============
// 64 bt-rows per block, 4 waves x 16 rows. lm_W hi-frags pre-swizzled in LDS.
// 2-term: (h_hi + h_lo) . W_hi  (verified absmax ~2e-3 in R4).
__global__ __launch_bounds__(256) void lstm_logits(
    const uint32_t* __restrict__ h_pack,
    const float*    __restrict__ lm_W,
    const float*    __restrict__ lm_b,
    float*          __restrict__ out)
{
    __shared__ __align__(16) ushort bf_lds[17 * 2 * 512];
    __shared__ float lmb_lds[VOCABSZ];

    const int tid = threadIdx.x;
    // stage lm_W hi-frags: frag (n,kt): lane l, elem e -> B[k=kt*32+(l>>4)*8+e][col=n*16+(l&15)]
    for (int i = tid; i < 17 * 2 * 64; i += 256) {
        const int n = i >> 7, rem = i & 127, kt = rem >> 6, l = rem & 63;
        const int col = n * 16 + (l & 15);
        const int k0  = kt * 32 + (l >> 4) * 8;
        short8 h8;
        if (col < VOCABSZ) {
            const float4 f0 = *(const float4*)(lm_W + col * HDIM + k0);
            const float4 f1 = *(const float4*)(lm_W + col * HDIM + k0 + 4);
            const float fv[8] = {f0.x, f0.y, f0.z, f0.w, f1.x, f1.y, f1.z, f1.w};
#pragma unroll
            for (int e = 0; e < 8; ++e) h8[e] = (short)f2bf(fv[e]);
        } else {
#pragma unroll
            for (int e = 0; e < 8; ++e) h8[e] = 0;
        }
        *(short8*)(bf_lds + (n * 2 + kt) * 512 + l * 8) = h8;
    }
    for (int i = tid; i < VOCABSZ; i += 256) lmb_lds[i] = lm_b[i];
    __syncthreads();

    const int wave = tid >> 6;
    const int lane = tid & 63;
    const int lmod = lane & 15;
    const int lhi  = lane >> 4;
    const size_t row0 = (size_t)blockIdx.x * 64 + wave * 16;

    // A-frags: lane = row lmod, k = kt*32 + lhi*8 + e
    short8 ah[2], al[2];
#pragma unroll
    for (int kt = 0; kt < 2; ++kt) {
        const uint32_t* src = h_pack + (row0 + lmod) * HDIM + kt * 32 + lhi * 8;
        const uint4 q0 = *(const uint4*)(src);
        const uint4 q1 = *(const uint4*)(src + 4);
        const uint32_t q[8] = {q0.x, q0.y, q0.z, q0.w, q1.x, q1.y, q1.z, q1.w};
        short8 a_, b_;
#pragma unroll
        for (int e = 0; e < 8; ++e) {
            a_[e] = (short)(q[e] & 0xffffu);
            b_[e] = (short)(q[e] >> 16);
        }
        ah[kt] = a_; al[kt] = b_;
    }

#pragma unroll 4
    for (int n = 0; n < 17; ++n) {
        const short8 bh0 = *(const short8*)(bf_lds + (n * 2 + 0) * 512 + lane * 8);
        const short8 bh1 = *(const short8*)(bf_lds + (n * 2 + 1) * 512 + lane * 8);
        const int v = n * 16 + lmod;
        const float bias = (v < VOCABSZ) ? lmb_lds[v] : 0.f;
        f32x4 acc = {bias, bias, bias, bias};
        acc = __builtin_amdgcn_mfma_f32_16x16x32_bf16(ah[0], bh0, acc, 0, 0, 0);
        acc = __builtin_amdgcn_mfma_f32_16x16x32_bf16(al[0], bh0, acc, 0, 0, 0);
        acc = __builtin_amdgcn_mfma_f32_16x16x32_bf16(ah[1], bh1, acc, 0, 0, 0);
        acc = __builtin_amdgcn_mfma_f32_16x16x32_bf16(al[1], bh1, acc, 0, 0, 0);
        if (v < VOCABSZ) {
#pragma unroll
            for (int e = 0; e < 4; ++e)
                out[(row0 + lhi * 4 + e) * VOCABSZ + v] = acc[e];
        }
    }
}

// ================= Fallback: R3 fused kernel (used only if ws too small) =====
__global__ __launch_bounds__(512) void lstm_fused_fb(
    const int*   __restrict__ idx,
    const float* __restrict__ wte,
    const float* __restrict__ W_ih,
    const float* __restrict__ W_hh,
    const float* __restrict__ b_ih,
    const float* __restrict__ b_hh,
    const float* __restrict__ lm_W,
    const float* __restrict__ lm_b,
    float*       __restrict__ out)
{
    __shared__ __align__(16) ushort a_hi[16 * 128];
    __shared__ __align__(16) ushort a_lo[16 * 128];
    __shared__ float g_lds[8 * 260];
    __shared__ int   idx_lds[8][T_STEPS];

    const int tid  = threadIdx.x;
    const int wave = tid >> 6;
    const int lane = tid & 63;
    const int lmod = lane & 15;
    const int lhi  = lane >> 4;
    const int rbase = blockIdx.x * 8;

    short8 wbh[2][4], wbl[2][4];
    float  gbias[2];
#pragma unroll
    for (int n = 0; n < 2; ++n) {
        const int col = wave * 32 + n * 16 + lmod;
        gbias[n] = b_ih[col] + b_hh[col];
#pragma unroll
        for (int kt = 0; kt < 4; ++kt) {
            const int k0 = (kt & 1) * 32 + lhi * 8;
            const float* src = (kt < 2 ? W_ih : W_hh) + col * HDIM + k0;
            short8 h8, l8;
#pragma unroll
            for (int e = 0; e < 8; ++e) {
                float f   = src[e];
                ushort hh = f2bf(f);
                h8[e] = (short)hh;
                l8[e] = (short)f2bf(f - bf2f(hh));
            }
            wbh[n][kt] = h8; wbl[n][kt] = l8;
        }
    }
    short8 lmh[2][2];
    float  lmbias[2];
#pragma unroll
    for (int ni = 0; ni < 2; ++ni) {
        const int v = (2 * wave + ni) * 16 + lmod;
        lmbias[ni] = lm_b[v];
#pragma unroll
        for (int kt = 0; kt < 2; ++kt) {
            const int k0 = kt * 32 + lhi * 8;
            short8 h8;
#pragma unroll
            for (int e = 0; e < 8; ++e) h8[e] = (short)f2bf(lm_W[v * HDIM + k0 + e]);
            lmh[ni][kt] = h8;
        }
    }
    const float w256r = lm_W[256 * HDIM + lane];
    const float b256  = lm_b[256];

    for (int i = tid; i < 16 * 128; i += 512) { a_hi[i] = 0; a_lo[i] = 0; }
    for (int i = tid; i < 8 * T_STEPS; i += 512) {
        const int r = i / T_STEPS, tt = i % T_STEPS;
        idx_lds[r][tt] = idx[(rbase + r) * T_STEPS + tt];
    }
    __syncthreads();
    if (tid < 8 * 16) {
        const int r = tid >> 4, j4 = (tid & 15) * 4;
        const int token = idx_lds[r][0];
        const float4 vv = *(const float4*)(wte + (size_t)token * HDIM + j4);
        const float fv[4] = {vv.x, vv.y, vv.z, vv.w};
#pragma unroll
        for (int e = 0; e < 4; ++e) {
            const ushort hh = f2bf(fv[e]);
            const int ix = (r * 128 + j4 + e) ^ ((r & 7) << 3);
            a_hi[ix] = hh;
            a_lo[ix] = f2bf(fv[e] - bf2f(hh));
        }
    }
    __syncthreads();

    float cstate = 0.f;
    for (int t = 0; t < T_STEPS; ++t) {
        f32x4 acc0 = {gbias[0], gbias[0], gbias[0], gbias[0]};
        f32x4 acc1 = {gbias[1], gbias[1], gbias[1], gbias[1]};
#pragma unroll
        for (int kt = 0; kt < 4; ++kt) {
            const int ix = (lmod * 128 + kt * 32 + lhi * 8) ^ ((lmod & 7) << 3);
            const short8 ah = *(const short8*)(a_hi + ix);
            const short8 al = *(const short8*)(a_lo + ix);
            acc0 = __builtin_amdgcn_mfma_f32_16x16x32_bf16(ah, wbh[0][kt], acc0, 0, 0, 0);
            acc0 = __builtin_amdgcn_mfma_f32_16x16x32_bf16(ah, wbl[0][kt], acc0, 0, 0, 0);
            acc0 = __builtin_amdgcn_mfma_f32_16x16x32_bf16(al, wbh[0][kt], acc0, 0, 0, 0);
            acc1 = __builtin_amdgcn_mfma_f32_16x16x32_bf16(ah, wbh[1][kt], acc1, 0, 0, 0);
            acc1 = __builtin_amdgcn_mfma_f32_16x16x32_bf16(ah, wbl[1][kt], acc1, 0, 0, 0);
            acc1 = __builtin_amdgcn_mfma_f32_16x16x32_bf16(al, wbh[1][kt], acc1, 0, 0, 0);
        }
        if (lhi < 2) {
#pragma unroll
            for (int e = 0; e < 4; ++e) {
                const int row = lhi * 4 + e;
                g_lds[row * 260 + wave * 32 + lmod]      = acc0[e];
                g_lds[row * 260 + wave * 32 + 16 + lmod] = acc1[e];
            }
        }
        __syncthreads();
        float4 vv;
        const bool do_stage = (t + 1 < T_STEPS) && (tid < 8 * 16);
        const int sr = tid >> 4, sj4 = (tid & 15) * 4;
        if (do_stage) {
            const int token = idx_lds[sr][t + 1];
            vv = *(const float4*)(wte + (size_t)token * HDIM + sj4);
        }
        {
            const float* gr = g_lds + wave * 260;
            const float iv = gr[lane];
            const float fv = gr[64 + lane];
            const float gv = gr[128 + lane];
            const float ov = gr[192 + lane];
            const float cn = sig_(fv) * cstate + sig_(iv) * tanh_(gv);
            cstate = cn;
            const float hv = sig_(ov) * tanh_(cn);
            const ushort hh = f2bf(hv);
            const int ix = (wave * 128 + 64 + lane) ^ ((wave & 7) << 3);
            a_hi[ix] = hh;
            a_lo[ix] = f2bf(hv - bf2f(hh));
            float p256 = hv * w256r;
#pragma unroll
            for (int off = 32; off; off >>= 1) p256 += __shfl_xor(p256, off);
            if (lane == 0)
                out[(size_t)(rbase + wave) * (T_STEPS * VOCABSZ) + (size_t)t * VOCABSZ + 256]
                    = p256 + b256;
        }
        if (do_stage) {
            const float fv[4] = {vv.x, vv.y, vv.z, vv.w};
#pragma unroll
            for (int e = 0; e < 4; ++e) {
                const ushort hh = f2bf(fv[e]);
                const int ix = (sr * 128 + sj4 + e) ^ ((sr & 7) << 3);
                a_hi[ix] = hh;
                a_lo[ix] = f2bf(fv[e] - bf2f(hh));
            }
        }
        __syncthreads();
        short8 lah[2], lal[2];
#pragma unroll
        for (int kt = 0; kt < 2; ++kt) {
            const int ix = (lmod * 128 + 64 + kt * 32 + lhi * 8) ^ ((lmod & 7) << 3);
            lah[kt] = *(const short8*)(a_hi + ix);
            lal[kt] = *(const short8*)(a_lo + ix);
        }
#pragma unroll
        for (int ni = 0; ni < 2; ++ni) {
            f32x4 acc = {lmbias[ni], lmbias[ni], lmbias[ni], lmbias[ni]};
#pragma unroll
            for (int kt = 0; kt < 2; ++kt) {
                acc = __builtin_amdgcn_mfma_f32_16x16x32_bf16(lah[kt], lmh[ni][kt], acc, 0, 0, 0);
                acc = __builtin_amdgcn_mfma_f32_16x16x32_bf16(lal[kt], lmh[ni][kt], acc, 0, 0, 0);
            }
            const int v = (2 * wave + ni) * 16 + lmod;
            if (lhi < 2) {
#pragma unroll
                for (int e = 0; e < 4; ++e) {
                    const int r = rbase + lhi * 4 + e;
                    out[(size_t)r * (T_STEPS * VOCABSZ) + (size_t)t * VOCABSZ + v] = acc[e];
                }
            }
        }
    }
}

extern "C" void kernel_launch(void* const* d_in, const int* in_sizes, int n_in,
                              void* d_out, int out_size, void* d_ws, size_t ws_size,
                              hipStream_t stream) {
    const int*   idx  = (const int*)  d_in[0];
    const float* wte  = (const float*)d_in[1];
    const float* W_ih = (const float*)d_in[2];
    const float* W_hh = (const float*)d_in[3];
    const float* b_ih = (const float*)d_in[4];
    const float* b_hh = (const float*)d_in[5];
    const float* lm_W = (const float*)d_in[6];
    const float* lm_b = (const float*)d_in[7];
    float* out = (float*)d_out;

    const int B = in_sizes[0] / T_STEPS;                 // 4096
    const size_t need = (size_t)B * T_STEPS * HDIM * 4;  // 90 MB h_pack

    if (ws_size >= need) {
        uint32_t* h_pack = (uint32_t*)d_ws;
        lstm_recur<<<B / 16, 512, 0, stream>>>(idx, wte, W_ih, W_hh, b_ih, b_hh, h_pack);
        lstm_logits<<<(B * T_STEPS) / 64, 256, 0, stream>>>(h_pack, lm_W, lm_b, out);
    } else {
        lstm_fused_fb<<<B / 8, 512, 0, stream>>>(idx, wte, W_ih, W_hh, b_ih, b_hh,
                                                 lm_W, lm_b, out);
    }
}